// Round 7
// baseline (4173.796 us; speedup 1.0000x reference)
//
#include <hip/hip_runtime.h>
#include <stdint.h>
#include <stddef.h>

#define B_SZ   2
#define N_PTS  15000
#define MPT    1024
#define CSEED  512
#define HMINF (-0.02f)
#define HMAXF (0.06f)

typedef __attribute__((ext_vector_type(8))) short bf16x8;
typedef __attribute__((ext_vector_type(4))) float f32x4;

__device__ inline unsigned short f2bf(float f) {
    unsigned u = __float_as_uint(f);
    unsigned r = (u + 0x7fffu + ((u >> 16) & 1u)) >> 16;   // RNE, finite inputs
    return (unsigned short)r;
}

// ---------------------------------------------------------------- mask dtype detect
__global__ void k_detect(const unsigned int* mraw, int* mode_out) {
    __shared__ int vi, vf;
    if (threadIdx.x == 0) { vi = 0; vf = 0; }
    __syncthreads();
    int li = 0, lf = 0;
    for (int i = threadIdx.x; i < (B_SZ * N_PTS) / 4; i += blockDim.x) {
        unsigned int u = mraw[i];
        if (u != 0u && u != 1u) li = 1;
        if (u != 0u && u != 0x3F800000u) lf = 1;
    }
    if (li) atomicOr(&vi, 1);
    if (lf) atomicOr(&vf, 1);
    __syncthreads();
    if (threadIdx.x == 0) *mode_out = (vi == 0) ? 0 : ((vf == 0) ? 1 : 2);
}

// ---------------------------------------------------------------- masked FPS v7
// Single-wave main loop: 512 threads set up (histogram, Morton scatter, cell
// bboxes), then wave 0 alone runs 1024 iterations with NO barriers. Cell meta
// (bbox/cmax/cidx/candidate) cached in lane registers (lane l owns cells
// 2l, 2l+1); points + pd LDS-resident, conflict-free layouts; DPP argmax with
// tie fast-path; far-point broadcast via readlane (SGPR).
#define FPS_T     512
#define FPS_CAP   7936          // 124 cells x 64 pts; Mc>CAP -> exact fallback
#define NCELL_MAX 124

__device__ inline unsigned dpp_max_u32(unsigned v) {   // valid in lane 63
    unsigned t;
    t = (unsigned)__builtin_amdgcn_update_dpp(0, (int)v, 0x111, 0xf, 0xf, false); v = v > t ? v : t;
    t = (unsigned)__builtin_amdgcn_update_dpp(0, (int)v, 0x112, 0xf, 0xf, false); v = v > t ? v : t;
    t = (unsigned)__builtin_amdgcn_update_dpp(0, (int)v, 0x114, 0xf, 0xf, false); v = v > t ? v : t;
    t = (unsigned)__builtin_amdgcn_update_dpp(0, (int)v, 0x118, 0xf, 0xf, false); v = v > t ? v : t;
    t = (unsigned)__builtin_amdgcn_update_dpp(0, (int)v, 0x142, 0xf, 0xf, false); v = v > t ? v : t;
    t = (unsigned)__builtin_amdgcn_update_dpp(0, (int)v, 0x143, 0xf, 0xf, false); v = v > t ? v : t;
    return v;
}
__device__ inline int dpp_min_i32(int v) {             // valid in lane 63
    int t;
    t = __builtin_amdgcn_update_dpp(0x7fffffff, v, 0x111, 0xf, 0xf, false); v = v < t ? v : t;
    t = __builtin_amdgcn_update_dpp(0x7fffffff, v, 0x112, 0xf, 0xf, false); v = v < t ? v : t;
    t = __builtin_amdgcn_update_dpp(0x7fffffff, v, 0x114, 0xf, 0xf, false); v = v < t ? v : t;
    t = __builtin_amdgcn_update_dpp(0x7fffffff, v, 0x118, 0xf, 0xf, false); v = v < t ? v : t;
    t = __builtin_amdgcn_update_dpp(0x7fffffff, v, 0x142, 0xf, 0xf, false); v = v < t ? v : t;
    t = __builtin_amdgcn_update_dpp(0x7fffffff, v, 0x143, 0xf, 0xf, false); v = v < t ? v : t;
    return v;
}
__device__ inline float dpp_fmax64(float v) {          // valid in lane 63
    int t;
    t = __builtin_amdgcn_update_dpp((int)0xFF800000, __float_as_int(v), 0x111, 0xf, 0xf, false); v = fmaxf(v, __int_as_float(t));
    t = __builtin_amdgcn_update_dpp((int)0xFF800000, __float_as_int(v), 0x112, 0xf, 0xf, false); v = fmaxf(v, __int_as_float(t));
    t = __builtin_amdgcn_update_dpp((int)0xFF800000, __float_as_int(v), 0x114, 0xf, 0xf, false); v = fmaxf(v, __int_as_float(t));
    t = __builtin_amdgcn_update_dpp((int)0xFF800000, __float_as_int(v), 0x118, 0xf, 0xf, false); v = fmaxf(v, __int_as_float(t));
    t = __builtin_amdgcn_update_dpp((int)0xFF800000, __float_as_int(v), 0x142, 0xf, 0xf, false); v = fmaxf(v, __int_as_float(t));
    t = __builtin_amdgcn_update_dpp((int)0xFF800000, __float_as_int(v), 0x143, 0xf, 0xf, false); v = fmaxf(v, __int_as_float(t));
    return v;
}
__device__ inline float dpp_fmin64(float v) {          // valid in lane 63
    int t;
    t = __builtin_amdgcn_update_dpp(0x7F800000, __float_as_int(v), 0x111, 0xf, 0xf, false); v = fminf(v, __int_as_float(t));
    t = __builtin_amdgcn_update_dpp(0x7F800000, __float_as_int(v), 0x112, 0xf, 0xf, false); v = fminf(v, __int_as_float(t));
    t = __builtin_amdgcn_update_dpp(0x7F800000, __float_as_int(v), 0x114, 0xf, 0xf, false); v = fminf(v, __int_as_float(t));
    t = __builtin_amdgcn_update_dpp(0x7F800000, __float_as_int(v), 0x118, 0xf, 0xf, false); v = fminf(v, __int_as_float(t));
    t = __builtin_amdgcn_update_dpp(0x7F800000, __float_as_int(v), 0x142, 0xf, 0xf, false); v = fminf(v, __int_as_float(t));
    t = __builtin_amdgcn_update_dpp(0x7F800000, __float_as_int(v), 0x143, 0xf, 0xf, false); v = fminf(v, __int_as_float(t));
    return v;
}

__global__ __launch_bounds__(FPS_T, 1) void k_fps(
        const void* mask_raw, const int* mode_p, const float* seed_xyz,
        float4* cp, int* fps_idx)
{
    const int b    = blockIdx.x;
    const int tid  = threadIdx.x;
    const int wv   = tid >> 6;
    const int lane = tid & 63;
    const int mode = *mode_p;
    const int cpb  = b * 15008;

    __shared__ float4 ptsL[FPS_CAP];           // 126976 B (fallback: pd overlay)
    __shared__ float  s_pd[FPS_CAP];           // 31744 B (setup: s_cell overlay)
    __shared__ float  s_meta[NCELL_MAX * 6];   // 2976 B  (bbox min/max per cell)
    __shared__ float4 s_pub4[2][8];
    __shared__ int    s_pubi[2][8];
    __shared__ int    s_wt[8];
    __shared__ int    s_total, s_start;
    __shared__ float  s_f[3];

    int* s_cell = (int*)s_pd;                  // 512 ints, setup-only overlay

    if (tid == 0) s_start = 0x7fffffff;
    s_cell[tid] = 0;
    __syncthreads();

    auto rd_mask = [&](int i) -> bool {
        if (mode == 0) return ((const int*)mask_raw)[b * N_PTS + i] != 0;
        if (mode == 1) return ((const unsigned int*)mask_raw)[b * N_PTS + i] != 0u;
        return ((const unsigned char*)mask_raw)[b * N_PTS + i] != 0;
    };
    auto cell_of = [&](float x, float y, float z) -> int {  // Morton 8x8x8
        int cx = (int)(x * 40.f); cx = cx < 0 ? 0 : (cx > 7 ? 7 : cx);
        int cy = (int)(y * 40.f); cy = cy < 0 ? 0 : (cy > 7 ? 7 : cy);
        int cz = (int)(z * 40.f); cz = cz < 0 ? 0 : (cz > 7 ? 7 : cz);
        int m = 0;
        #pragma unroll
        for (int q = 0; q < 3; ++q)
            m |= (((cx >> q) & 1) << (3*q+2)) | (((cy >> q) & 1) << (3*q+1)) | (((cz >> q) & 1) << (3*q));
        return m;
    };

    // pass 1: histogram + first masked index
    int myfirst = 0x7fffffff;
    for (int k = 0; k < 30; ++k) {
        int i = tid + k * FPS_T;
        if (i < N_PTS && rd_mask(i)) {
            if (i < myfirst) myfirst = i;
            float x = seed_xyz[(size_t)(b * N_PTS + i) * 3 + 0];
            float y = seed_xyz[(size_t)(b * N_PTS + i) * 3 + 1];
            float z = seed_xyz[(size_t)(b * N_PTS + i) * 3 + 2];
            atomicAdd(&s_cell[cell_of(x, y, z)], 1);
        }
    }
    if (myfirst != 0x7fffffff) atomicMin(&s_start, myfirst);
    __syncthreads();
    // parallel exclusive prefix over 512 grid cells
    {
        int v = s_cell[tid];
        int inc = v;
        #pragma unroll
        for (int d = 1; d < 64; d <<= 1) {
            int o = __shfl_up(inc, d, 64);
            if (lane >= d) inc += o;
        }
        if (lane == 63) s_wt[wv] = inc;
        __syncthreads();
        int off = 0;
        #pragma unroll
        for (int w = 0; w < 8; ++w) off += (w < wv) ? s_wt[w] : 0;
        s_cell[tid] = off + inc - v;
        if (tid == FPS_T - 1) s_total = off + inc;
    }
    __syncthreads();
    const int Mc = s_total;
    const int start = s_start;
    if (Mc == 0) {
        for (int m = tid; m < MPT; m += FPS_T) fps_idx[b * MPT + m] = 0;
        return;
    }

    // pass 2: scatter Morton-sorted into LDS (+ global mirror for fallback)
    for (int k = 0; k < 30; ++k) {
        int i = tid + k * FPS_T;
        if (i < N_PTS && rd_mask(i)) {
            float x = seed_xyz[(size_t)(b * N_PTS + i) * 3 + 0];
            float y = seed_xyz[(size_t)(b * N_PTS + i) * 3 + 1];
            float z = seed_xyz[(size_t)(b * N_PTS + i) * 3 + 2];
            int pos = atomicAdd(&s_cell[cell_of(x, y, z)], 1);
            float4 v4 = make_float4(x, y, z, __int_as_float(i));
            cp[cpb + pos] = v4;
            if (pos < FPS_CAP) ptsL[pos] = v4;
            if (i == start) { s_f[0] = x; s_f[1] = y; s_f[2] = z; }
        }
    }
    __threadfence_block();
    __syncthreads();

    if (Mc <= FPS_CAP) {
        // ================= main path: single-wave loop =================
        const int ncell = (Mc + 63) >> 6;

        // one-time: per-cell bbox via wave DPP reduce -> s_meta
        for (int c = wv; c < ncell; c += 8) {
            bool val = (c * 64 + lane) < Mc;
            float4 v = ptsL[c * 64 + lane];
            float mnx = val ? v.x : 1e30f, mny = val ? v.y : 1e30f, mnz = val ? v.z : 1e30f;
            float mxx = val ? v.x : -1e30f, mxy = val ? v.y : -1e30f, mxz = val ? v.z : -1e30f;
            mnx = dpp_fmin64(mnx); mny = dpp_fmin64(mny); mnz = dpp_fmin64(mnz);
            mxx = dpp_fmax64(mxx); mxy = dpp_fmax64(mxy); mxz = dpp_fmax64(mxz);
            if (lane == 63) {
                s_meta[c*6+0] = mnx; s_meta[c*6+1] = mny; s_meta[c*6+2] = mnz;
                s_meta[c*6+3] = mxx; s_meta[c*6+4] = mxy; s_meta[c*6+5] = mxz;
            }
        }
        __syncthreads();
        for (int i = tid; i < (ncell << 6); i += FPS_T) s_pd[i] = 1e10f;
        __syncthreads();

        if (wv == 0) {
            const int cA = 2 * lane, cB = 2 * lane + 1;
            const bool hA = cA < ncell, hB = cB < ncell;
            float Anx=0.f,Any=0.f,Anz=0.f,Axx=0.f,Axy=0.f,Axz=0.f;
            float Bnx=0.f,Bny=0.f,Bnz=0.f,Bxx=0.f,Bxy=0.f,Bxz=0.f;
            if (hA) {
                Anx = s_meta[cA*6+0]; Any = s_meta[cA*6+1]; Anz = s_meta[cA*6+2];
                Axx = s_meta[cA*6+3]; Axy = s_meta[cA*6+4]; Axz = s_meta[cA*6+5];
            }
            if (hB) {
                Bnx = s_meta[cB*6+0]; Bny = s_meta[cB*6+1]; Bnz = s_meta[cB*6+2];
                Bxx = s_meta[cB*6+3]; Bxy = s_meta[cB*6+4]; Bxz = s_meta[cB*6+5];
            }
            // register cell cache: max pd (cmax), argmax idx, candidate coords
            float Acm = hA ? 1e10f : -1.f; int Aci = 0x7fffffff;
            float Acx=0.f, Acy=0.f, Acz=0.f;
            float Bcm = hB ? 1e10f : -1.f; int Bci = 0x7fffffff;
            float Bcx=0.f, Bcy=0.f, Bcz=0.f;

            float fx = s_f[0], fy = s_f[1], fz = s_f[2];
            int widx = start;

            #pragma unroll 1
            for (int m = 0; m < MPT; ++m) {
                if (lane == 0) fps_idx[b * MPT + m] = widx;

                // register-only skip scan (exact: skip only if no pd can change)
                float exA = fmaxf(fmaxf(Anx - fx, fx - Axx), 0.f);
                float eyA = fmaxf(fmaxf(Any - fy, fy - Axy), 0.f);
                float ezA = fmaxf(fmaxf(Anz - fz, fz - Axz), 0.f);
                float dmA = (exA*exA + eyA*eyA + ezA*ezA) * 0.99999f;
                float exB = fmaxf(fmaxf(Bnx - fx, fx - Bxx), 0.f);
                float eyB = fmaxf(fmaxf(Bny - fy, fy - Bxy), 0.f);
                float ezB = fmaxf(fmaxf(Bnz - fz, fz - Bxz), 0.f);
                float dmB = (exB*exB + eyB*eyB + ezB*ezB) * 0.99999f;
                bool actA = hA && (dmA < Acm);
                bool actB = hB && (dmB < Bcm);
                unsigned long long balA = __ballot(actA);
                unsigned long long balB = __ballot(actB);

                #pragma unroll 1
                for (int half = 0; half < 2; ++half) {
                    unsigned long long rem = half ? balB : balA;
                    while (rem) {                      // wave-uniform
                        int l0 = __ffsll(rem) - 1;
                        rem &= rem - 1;
                        int c = 2 * l0 + half;
                        int pb = (c << 6) + lane;
                        bool vld = pb < Mc;
                        float4 v = ptsL[pb];
                        float pdv = s_pd[pb];
                        float dx = __fsub_rn(v.x, fx);
                        float dy = __fsub_rn(v.y, fy);
                        float dz = __fsub_rn(v.z, fz);
                        float d  = __fadd_rn(__fadd_rn(__fmul_rn(dx, dx), __fmul_rn(dy, dy)),
                                             __fmul_rn(dz, dz));
                        float nd = fminf(pdv, d);
                        if (vld) s_pd[pb] = nd;
                        int ai = __float_as_int(v.w);
                        unsigned vb = vld ? __float_as_uint(nd) : 0u;
                        unsigned cmx = (unsigned)__builtin_amdgcn_readlane((int)dpp_max_u32(vb), 63);
                        unsigned long long tb = __ballot(vld && vb == cmx);
                        int wl;
                        if (__popcll(tb) == 1) {
                            wl = __ffsll(tb) - 1;      // unique max: skip idx chain
                        } else {
                            int ic = (vld && vb == cmx) ? ai : 0x7fffffff;
                            int cid = __builtin_amdgcn_readlane(dpp_min_i32(ic), 63);
                            wl = __ffsll(__ballot(vld && ai == cid)) - 1;
                        }
                        float ncm = __uint_as_float(cmx);
                        int   nci = __builtin_amdgcn_readlane(ai, wl);
                        float ncx = __int_as_float(__builtin_amdgcn_readlane(__float_as_int(v.x), wl));
                        float ncy = __int_as_float(__builtin_amdgcn_readlane(__float_as_int(v.y), wl));
                        float ncz = __int_as_float(__builtin_amdgcn_readlane(__float_as_int(v.z), wl));
                        if (lane == l0) {              // owner lane updates cache
                            if (half == 0) { Acm = ncm; Aci = nci; Acx = ncx; Acy = ncy; Acz = ncz; }
                            else           { Bcm = ncm; Bci = nci; Bcx = ncx; Bcy = ncy; Bcz = ncz; }
                        }
                    }
                }

                // per-lane candidate = best of owned cells (val desc, idx asc)
                bool pA = (Acm > Bcm) || (Acm == Bcm && Aci < Bci);
                float cv = pA ? Acm : Bcm;
                int   ci = pA ? Aci : Bci;
                float cx = pA ? Acx : Bcx;
                float cy = pA ? Acy : Bcy;
                float cz = pA ? Acz : Bcz;
                unsigned v2 = (cv >= 0.f) ? __float_as_uint(cv) : 0u;
                unsigned wm = (unsigned)__builtin_amdgcn_readlane((int)dpp_max_u32(v2), 63);
                unsigned long long t2 = __ballot(v2 == wm);
                int wl2, gi;
                if (__popcll(t2) == 1) {
                    wl2 = __ffsll(t2) - 1;
                    gi = __builtin_amdgcn_readlane(ci, wl2);
                } else {
                    int ic2 = (v2 == wm) ? ci : 0x7fffffff;
                    gi = __builtin_amdgcn_readlane(dpp_min_i32(ic2), 63);
                    wl2 = __ffsll(__ballot(v2 == wm && ci == gi)) - 1;
                }
                fx = __int_as_float(__builtin_amdgcn_readlane(__float_as_int(cx), wl2));
                fy = __int_as_float(__builtin_amdgcn_readlane(__float_as_int(cy), wl2));
                fz = __int_as_float(__builtin_amdgcn_readlane(__float_as_int(cz), wl2));
                widx = gi;
            }
        }
        __syncthreads();                       // waves 1..7 park here
    } else {
        // ============ fallback (Mc > 7936): L2 coords, LDS pd ============
        const int L = (Mc + FPS_T - 1) / FPS_T;
        float* pdL = (float*)ptsL;             // Mc <= 15000 -> 60 KB
        for (int c = tid; c < Mc; c += FPS_T) pdL[c] = 1e10f;
        if (lane == 0) {
            s_pub4[0][wv] = make_float4(-1.f, 0.f, 0.f, 0.f);
            s_pub4[1][wv] = make_float4(-1.f, 0.f, 0.f, 0.f);
            s_pubi[0][wv] = 0x7fffffff;
            s_pubi[1][wv] = 0x7fffffff;
        }
        __syncthreads();
        float fx = s_f[0], fy = s_f[1], fz = s_f[2];
        int widx = start;
        int par = 0;
        for (int m = 0; m < MPT; ++m) {
            if (tid == 0) fps_idx[b * MPT + m] = widx;
            float nv = -1.f; int ni = 0x7fffffff;
            float nx = 0.f, ny = 0.f, nz = 0.f;
            for (int k = 0; k < L; ++k) {
                int c = tid * L + k;
                if (c < Mc) {
                    float4 v = cp[cpb + c];
                    float dx = __fsub_rn(v.x, fx);
                    float dy = __fsub_rn(v.y, fy);
                    float dz = __fsub_rn(v.z, fz);
                    float d  = __fadd_rn(__fadd_rn(__fmul_rn(dx, dx), __fmul_rn(dy, dy)),
                                         __fmul_rn(dz, dz));
                    float nd = fminf(pdL[c], d);
                    pdL[c] = nd;
                    int oi = __float_as_int(v.w);
                    bool bt = (nd > nv) || (nd == nv && oi < ni);
                    nv = bt ? nd : nv; ni = bt ? oi : ni;
                    nx = bt ? v.x : nx; ny = bt ? v.y : ny; nz = bt ? v.z : nz;
                }
            }
            unsigned vb = (nv >= 0.f) ? __float_as_uint(nv) : 0u;
            unsigned wmax = (unsigned)__builtin_amdgcn_readlane((int)dpp_max_u32(vb), 63);
            int icand = (vb == wmax) ? ni : 0x7fffffff;
            int wmin = __builtin_amdgcn_readlane(dpp_min_i32(icand), 63);
            if ((vb == wmax) && (ni == wmin) && vb != 0u) {
                s_pub4[par][wv] = make_float4(nv, nx, ny, nz);
                s_pubi[par][wv] = ni;
            }
            __syncthreads();
            {
                float bvv = -2.f; int bii = 0x7fffffff;
                float nfx = 0.f, nfy = 0.f, nfz = 0.f;
                #pragma unroll
                for (int w = 0; w < 8; ++w) {
                    float4 c4 = s_pub4[par][w];
                    int ci2 = s_pubi[par][w];
                    bool bt = (c4.x > bvv) || (c4.x == bvv && ci2 < bii);
                    bvv = bt ? c4.x : bvv; bii = bt ? ci2 : bii;
                    nfx = bt ? c4.y : nfx; nfy = bt ? c4.z : nfy; nfz = bt ? c4.w : nfz;
                }
                fx = nfx; fy = nfy; fz = nfz; widx = bii;
            }
            par ^= 1;
        }
    }
}

// ---------------------------------------------------------------- gathers
__global__ void k_gather(const float* seed_features, const float* seed_xyz,
                         const int* fps_idx, float* feat_g, float* xyz_g)
{
    int e = blockIdx.x;
    if (e < B_SZ * CSEED) {
        int b = e >> 9, c = e & (CSEED - 1);
        const float* src = seed_features + (size_t)(b * CSEED + c) * N_PTS;
        float* dst = feat_g + (size_t)(b * CSEED + c) * MPT;
        const int* idx = fps_idx + b * MPT;
        for (int m = threadIdx.x; m < MPT; m += blockDim.x) dst[m] = src[idx[m]];
    } else {
        int b = e - B_SZ * CSEED;
        const int* idx = fps_idx + b * MPT;
        for (int m = threadIdx.x; m < MPT; m += blockDim.x) {
            int p = idx[m];
            xyz_g[(size_t)(b * MPT + m) * 3 + 0] = seed_xyz[(size_t)(b * N_PTS + p) * 3 + 0];
            xyz_g[(size_t)(b * MPT + m) * 3 + 1] = seed_xyz[(size_t)(b * N_PTS + p) * 3 + 1];
            xyz_g[(size_t)(b * MPT + m) * 3 + 2] = seed_xyz[(size_t)(b * N_PTS + p) * 3 + 2];
        }
    }
}

// ---------------------------------------------------------------- W2 -> bf16 (same layout)
__global__ void k_w2bf(const float* crop_w2, unsigned short* w2bf) {
    int i = blockIdx.x * blockDim.x + threadIdx.x;
    if (i < 4 * 512 * 256) w2bf[i] = f2bf(crop_w2[i]);
}

// ---------------------------------------------------------------- F1T = feat_g^T * W1f^T + b1
__global__ __launch_bounds__(256) void k_f1(const float* feat_g, const float* crop_w1,
                                            const float* crop_b1, float* f1t)
{
    const int blk = blockIdx.x;
    const int pt = blk & 15;
    const int b  = (blk >> 4) & 1;
    const int s  = blk >> 5;
    const int p0 = pt * 64;
    __shared__ float A[16][64];
    __shared__ float Bm[16][256];
    const int tid = threadIdx.x;
    const int pg = tid & 15, og = tid >> 4;
    float acc[4][16];
    #pragma unroll
    for (int i = 0; i < 4; ++i)
        #pragma unroll
        for (int j = 0; j < 16; ++j) acc[i][j] = 0.f;

    for (int kc = 0; kc < CSEED; kc += 16) {
        __syncthreads();
        {
            int r = tid >> 4, pp = (tid & 15) * 4;
            *(float4*)&A[r][pp] =
                *(const float4*)&feat_g[(size_t)(b * CSEED + kc + r) * MPT + p0 + pp];
            #pragma unroll
            for (int r2 = 0; r2 < 16; ++r2)
                Bm[r2][tid] = crop_w1[(size_t)(s * 256 + tid) * 515 + 3 + kc + r2];
        }
        __syncthreads();
        #pragma unroll
        for (int r = 0; r < 16; ++r) {
            float4 a4 = *(const float4*)&A[r][pg * 4];
            float av[4] = {a4.x, a4.y, a4.z, a4.w};
            float bv[16];
            #pragma unroll
            for (int q = 0; q < 4; ++q) {
                float4 b4 = *(const float4*)&Bm[r][og * 16 + q * 4];
                bv[q*4+0] = b4.x; bv[q*4+1] = b4.y; bv[q*4+2] = b4.z; bv[q*4+3] = b4.w;
            }
            #pragma unroll
            for (int i = 0; i < 4; ++i)
                #pragma unroll
                for (int j = 0; j < 16; ++j)
                    acc[i][j] += av[i] * bv[j];
        }
    }
    #pragma unroll
    for (int i = 0; i < 4; ++i) {
        size_t row = (size_t)((s * B_SZ + b) * MPT + p0 + pg * 4 + i) * 256;
        #pragma unroll
        for (int q = 0; q < 4; ++q) {
            float4 o4;
            o4.x = acc[i][q*4+0] + crop_b1[s*256 + og*16 + q*4+0];
            o4.y = acc[i][q*4+1] + crop_b1[s*256 + og*16 + q*4+1];
            o4.z = acc[i][q*4+2] + crop_b1[s*256 + og*16 + q*4+2];
            o4.w = acc[i][q*4+3] + crop_b1[s*256 + og*16 + q*4+3];
            *(float4*)&f1t[row + og * 16 + q * 4] = o4;
        }
    }
}

// ---------------------------------------------------------------- local coords + neighbor select
__global__ __launch_bounds__(256) void k_select(const float* xyz_g, const float* views_rot,
                                                int* sel_idx, float* sel_xyz)
{
    const int wv = threadIdx.x >> 6;
    const int lane = threadIdx.x & 63;
    const int gj = blockIdx.x * 4 + wv;
    const int b = gj >> 10, j = gj & (MPT - 1);

    const float cx = xyz_g[(size_t)(b * MPT + j) * 3 + 0];
    const float cy = xyz_g[(size_t)(b * MPT + j) * 3 + 1];
    const float cz = xyz_g[(size_t)(b * MPT + j) * 3 + 2];
    const float* R = views_rot + (size_t)(b * MPT + j) * 9;
    const float r00 = R[0], r01 = R[1], r02 = R[2];
    const float r10 = R[3], r11 = R[4], r12 = R[5];
    const float r20 = R[6], r21 = R[7], r22 = R[8];

    const float R2C[4] = { (float)(0.025 * 0.025), (float)(0.0375 * 0.0375),
                           (float)(0.05 * 0.05),   (float)(0.075 * 0.075) };
    const int NSs[4] = {16, 32, 32, 64};

    __shared__ float s_zloc[4][3];
    __shared__ int   s_padk[4][4];
    __shared__ float s_padx[4][4][3];

    int cnt[4] = {0, 0, 0, 0};

    for (int ch = 0; ch < 16; ++ch) {
        int k = ch * 64 + lane;
        float x = xyz_g[(size_t)(b * MPT + k) * 3 + 0];
        float y = xyz_g[(size_t)(b * MPT + k) * 3 + 1];
        float z = xyz_g[(size_t)(b * MPT + k) * 3 + 2];
        float rx = __fsub_rn(x, cx), ry = __fsub_rn(y, cy), rz = __fsub_rn(z, cz);
        float l0 = __fadd_rn(__fadd_rn(__fmul_rn(rx, r00), __fmul_rn(ry, r10)), __fmul_rn(rz, r20));
        float l1 = __fadd_rn(__fadd_rn(__fmul_rn(rx, r01), __fmul_rn(ry, r11)), __fmul_rn(rz, r21));
        float l2 = __fadd_rn(__fadd_rn(__fmul_rn(rx, r02), __fmul_rn(ry, r12)), __fmul_rn(rz, r22));
        float r2 = __fadd_rn(__fmul_rn(l1, l1), __fmul_rn(l2, l2));
        bool inh = (l0 >= HMINF) && (l0 <= HMAXF);
        if (ch == 0 && lane == 0) { s_zloc[wv][0] = l0; s_zloc[wv][1] = l1; s_zloc[wv][2] = l2; }
        #pragma unroll
        for (int sc = 0; sc < 4; ++sc) {
            bool v = inh && (r2 < R2C[sc]);
            unsigned long long bal = __ballot(v);
            int pre = __popcll(bal & ((1ull << lane) - 1ull));
            int p = cnt[sc] + pre;
            if (v && p < NSs[sc]) {
                size_t sb = ((size_t)(sc * B_SZ + b) * MPT + j) * 64 + p;
                sel_idx[sb] = k;
                sel_xyz[sb * 3 + 0] = l0;
                sel_xyz[sb * 3 + 1] = l1;
                sel_xyz[sb * 3 + 2] = l2;
                if (p == 0) {
                    s_padk[wv][sc] = k;
                    s_padx[wv][sc][0] = l0; s_padx[wv][sc][1] = l1; s_padx[wv][sc][2] = l2;
                }
            }
            cnt[sc] += __popcll(bal);
        }
    }
    __syncthreads();
    #pragma unroll
    for (int sc = 0; sc < 4; ++sc) {
        int cs = cnt[sc];
        int pk; float a0, a1, a2;
        if (cs > 0) { pk = s_padk[wv][sc]; a0 = s_padx[wv][sc][0]; a1 = s_padx[wv][sc][1]; a2 = s_padx[wv][sc][2]; }
        else        { pk = 0; a0 = s_zloc[wv][0]; a1 = s_zloc[wv][1]; a2 = s_zloc[wv][2]; }
        for (int n = cs + lane; n < NSs[sc]; n += 64) {
            size_t sb = ((size_t)(sc * B_SZ + b) * MPT + j) * 64 + n;
            sel_idx[sb] = pk;
            sel_xyz[sb * 3 + 0] = a0; sel_xyz[sb * 3 + 1] = a1; sel_xyz[sb * 3 + 2] = a2;
        }
    }
}

// ---------------------------------------------------------------- crop MLP via bf16 MFMA
__global__ __launch_bounds__(256) void k_crop(
        const int s, const int ns, const int log2ns,
        const float* f1t, const float* crop_w1, const unsigned short* w2bf,
        const float* crop_b2, const int* sel_idx, const float* sel_xyz, float* vp_cat)
{
    const int tid = threadIdx.x;
    const int jt = 64 >> log2ns;
    const int nj = MPT / jt;
    const int b = blockIdx.x / nj;
    const int jbase = (blockIdx.x % nj) * jt;

    __shared__ unsigned short h1T[64 * 264];   // [col][c] bf16, stride 264
    __shared__ float w1xa[3 * 256];
    __shared__ float pooled[512 * 4];          // [o][wave]

    for (int i = tid; i < 768; i += 256) {
        int a = i >> 8, o = i & 255;
        w1xa[i] = crop_w1[(size_t)(s * 256 + o) * 515 + a];
    }
    __syncthreads();

    // phase 1: h1 = relu(f1row + W1x*xyz) -> bf16 -> h1T
    {
        const int col = tid & 63;
        const int cq = tid >> 6;
        const int jl = col >> log2ns;
        const int nn = col & (ns - 1);
        const size_t sb = ((size_t)(s * B_SZ + b) * MPT + jbase + jl) * 64 + nn;
        const int p = sel_idx[sb];
        const float gx = sel_xyz[sb * 3 + 0];
        const float gy = sel_xyz[sb * 3 + 1];
        const float gz = sel_xyz[sb * 3 + 2];
        const float* f1row = f1t + (size_t)((s * B_SZ + b) * MPT + p) * 256;
        #pragma unroll
        for (int c4 = 0; c4 < 16; ++c4) {
            int c0 = cq * 64 + c4 * 4;
            float4 fv = *(const float4*)&f1row[c0];
            float v0 = fmaxf(fv.x + w1xa[c0+0]*gx + w1xa[256+c0+0]*gy + w1xa[512+c0+0]*gz, 0.f);
            float v1 = fmaxf(fv.y + w1xa[c0+1]*gx + w1xa[256+c0+1]*gy + w1xa[512+c0+1]*gz, 0.f);
            float v2 = fmaxf(fv.z + w1xa[c0+2]*gx + w1xa[256+c0+2]*gy + w1xa[512+c0+2]*gz, 0.f);
            float v3 = fmaxf(fv.w + w1xa[c0+3]*gx + w1xa[256+c0+3]*gy + w1xa[512+c0+3]*gz, 0.f);
            unsigned lo = (unsigned)f2bf(v0) | ((unsigned)f2bf(v1) << 16);
            unsigned hi = (unsigned)f2bf(v2) | ((unsigned)f2bf(v3) << 16);
            *(uint2*)&h1T[col * 264 + c0] = make_uint2(lo, hi);
        }
    }
    __syncthreads();

    // phase 2: per-wave MFMA over 32 o-tiles
    {
        const int wv = tid >> 6;
        const int lane = tid & 63;
        const int lm = lane & 15, lq = lane >> 4;

        bf16x8 afr[8];                         // h1 A-frags: loaded once
        #pragma unroll
        for (int kk = 0; kk < 8; ++kk)
            afr[kk] = *(const bf16x8*)&h1T[(wv * 16 + lm) * 264 + kk * 32 + lq * 8];

        const unsigned short* wbase = w2bf + (size_t)s * 512 * 256;
        auto ldb = [&](int ot, int kk) -> bf16x8 {
            return *(const bf16x8*)&wbase[(size_t)(ot * 16 + lm) * 256 + kk * 32 + lq * 8];
        };

        bf16x8 bbA[8], bbB[8];
        #pragma unroll
        for (int kk = 0; kk < 8; ++kk) bbA[kk] = ldb(0, kk);

        #pragma unroll 1
        for (int op = 0; op < 16; ++op) {
            const int ot0 = op * 2, ot1 = op * 2 + 1;
            #pragma unroll
            for (int kk = 0; kk < 8; ++kk) bbB[kk] = ldb(ot1, kk);
            {
                f32x4 acc = {0.f, 0.f, 0.f, 0.f};
                #pragma unroll
                for (int kk = 0; kk < 8; ++kk)
                    acc = __builtin_amdgcn_mfma_f32_16x16x32_bf16(afr[kk], bbA[kk], acc, 0, 0, 0);
                float mx = fmaxf(fmaxf(acc[0], acc[1]), fmaxf(acc[2], acc[3]));
                mx = fmaxf(mx, __shfl_xor(mx, 16, 64));
                mx = fmaxf(mx, __shfl_xor(mx, 32, 64));
                if (lane < 16) pooled[(ot0 * 16 + lane) * 4 + wv] = mx;
            }
            if (op < 15) {
                #pragma unroll
                for (int kk = 0; kk < 8; ++kk) bbA[kk] = ldb(ot1 + 1, kk);
            }
            {
                f32x4 acc = {0.f, 0.f, 0.f, 0.f};
                #pragma unroll
                for (int kk = 0; kk < 8; ++kk)
                    acc = __builtin_amdgcn_mfma_f32_16x16x32_bf16(afr[kk], bbB[kk], acc, 0, 0, 0);
                float mx = fmaxf(fmaxf(acc[0], acc[1]), fmaxf(acc[2], acc[3]));
                mx = fmaxf(mx, __shfl_xor(mx, 16, 64));
                mx = fmaxf(mx, __shfl_xor(mx, 32, 64));
                if (lane < 16) pooled[(ot1 * 16 + lane) * 4 + wv] = mx;
            }
        }
    }
    __syncthreads();

    // epilogue: combine wave partials per center, +b2, relu, store
    const int g = ns >> 4;                     // wave-slots per center: 1,2,4
    for (int t = tid; t < 512 * jt; t += 256) {
        int o = t & 511, j2 = t >> 9;
        float v = pooled[o * 4 + j2 * g];
        for (int q = 1; q < g; ++q) v = fmaxf(v, pooled[o * 4 + j2 * g + q]);
        v = fmaxf(v + crop_b2[s * 512 + o], 0.f);
        vp_cat[((size_t)(b * 4 + s) * 512 + o) * MPT + jbase + j2] = v;
    }
}

// ---------------------------------------------------------------- fuse + gate + output
__global__ __launch_bounds__(256) void k_out(
        const float* vp_cat, const float* feat_g,
        const float* fuse_w, const float* fuse_b,
        const float* gate_w, const float* gate_b, float* out)
{
    const int blk = blockIdx.x;
    const int mt = blk & 15, ot = (blk >> 4) & 3, b = blk >> 6;
    const int o0b = ot * 128, m0b = mt * 64;
    __shared__ float A[16 * 128];
    __shared__ float Bm[16 * 64];
    const int tid = threadIdx.x;
    const int og = tid >> 4, mg = tid & 15;
    float acc1[8][4], acc2[8][4];
    #pragma unroll
    for (int i = 0; i < 8; ++i)
        #pragma unroll
        for (int jq = 0; jq < 4; ++jq) { acc1[i][jq] = 0.f; acc2[i][jq] = 0.f; }

    for (int kc = 0; kc < 2048; kc += 16) {
        __syncthreads();
        {
            int oo = tid >> 1, r0 = (tid & 1) * 8;
            const float* srow = fuse_w + (size_t)(o0b + oo) * 2048 + kc + r0;
            float4 u0 = *(const float4*)srow;
            float4 u1 = *(const float4*)(srow + 4);
            A[(r0 + 0) * 128 + oo] = u0.x; A[(r0 + 1) * 128 + oo] = u0.y;
            A[(r0 + 2) * 128 + oo] = u0.z; A[(r0 + 3) * 128 + oo] = u0.w;
            A[(r0 + 4) * 128 + oo] = u1.x; A[(r0 + 5) * 128 + oo] = u1.y;
            A[(r0 + 6) * 128 + oo] = u1.z; A[(r0 + 7) * 128 + oo] = u1.w;
            int r = tid >> 4, mm = (tid & 15) * 4;
            *(float4*)&Bm[r * 64 + mm] =
                *(const float4*)&vp_cat[((size_t)b * 2048 + kc + r) * MPT + m0b + mm];
        }
        __syncthreads();
        #pragma unroll
        for (int r = 0; r < 16; ++r) {
            float4 a0 = *(const float4*)&A[r * 128 + og * 8];
            float4 a1 = *(const float4*)&A[r * 128 + og * 8 + 4];
            float4 bb = *(const float4*)&Bm[r * 64 + mg * 4];
            float av[8] = {a0.x,a0.y,a0.z,a0.w, a1.x,a1.y,a1.z,a1.w};
            float bv[4] = {bb.x, bb.y, bb.z, bb.w};
            #pragma unroll
            for (int oi = 0; oi < 8; ++oi)
                #pragma unroll
                for (int mi = 0; mi < 4; ++mi)
                    acc1[oi][mi] += av[oi] * bv[mi];
        }
    }
    for (int kc = 0; kc < 512; kc += 16) {
        __syncthreads();
        {
            int oo = tid >> 1, r0 = (tid & 1) * 8;
            const float* srow = gate_w + (size_t)(o0b + oo) * 512 + kc + r0;
            float4 u0 = *(const float4*)srow;
            float4 u1 = *(const float4*)(srow + 4);
            A[(r0 + 0) * 128 + oo] = u0.x; A[(r0 + 1) * 128 + oo] = u0.y;
            A[(r0 + 2) * 128 + oo] = u0.z; A[(r0 + 3) * 128 + oo] = u0.w;
            A[(r0 + 4) * 128 + oo] = u1.x; A[(r0 + 5) * 128 + oo] = u1.y;
            A[(r0 + 6) * 128 + oo] = u1.z; A[(r0 + 7) * 128 + oo] = u1.w;
            int r = tid >> 4, mm = (tid & 15) * 4;
            *(float4*)&Bm[r * 64 + mm] =
                *(const float4*)&feat_g[((size_t)b * CSEED + kc + r) * MPT + m0b + mm];
        }
        __syncthreads();
        #pragma unroll
        for (int r = 0; r < 16; ++r) {
            float4 a0 = *(const float4*)&A[r * 128 + og * 8];
            float4 a1 = *(const float4*)&A[r * 128 + og * 8 + 4];
            float4 bb = *(const float4*)&Bm[r * 64 + mg * 4];
            float av[8] = {a0.x,a0.y,a0.z,a0.w, a1.x,a1.y,a1.z,a1.w};
            float bv[4] = {bb.x, bb.y, bb.z, bb.w};
            #pragma unroll
            for (int oi = 0; oi < 8; ++oi)
                #pragma unroll
                for (int mi = 0; mi < 4; ++mi)
                    acc2[oi][mi] += av[oi] * bv[mi];
        }
    }
    #pragma unroll
    for (int oi = 0; oi < 8; ++oi) {
        int o = o0b + og * 8 + oi;
        float fb = fuse_b[o], gb = gate_b[o];
        #pragma unroll
        for (int mi = 0; mi < 4; ++mi) {
            int m = m0b + mg * 4 + mi;
            float f = acc1[oi][mi] + fb;
            float gl = acc2[oi][mi] + gb;
            float gt = 1.f / (1.f + __expf(-gl));
            float fg = feat_g[((size_t)b * CSEED + o) * MPT + m];
            out[((size_t)b * CSEED + o) * MPT + m] = f + gt * fg;
        }
    }
}

// ---------------------------------------------------------------- launcher
extern "C" void kernel_launch(void* const* d_in, const int* in_sizes, int n_in,
                              void* d_out, int out_size, void* d_ws, size_t ws_size,
                              hipStream_t stream) {
    const float* seed_xyz      = (const float*)d_in[0];
    const float* seed_features = (const float*)d_in[1];
    const void*  mask_raw      = d_in[2];
    const float* views_rot     = (const float*)d_in[3];
    const float* crop_w1       = (const float*)d_in[4];
    const float* crop_b1       = (const float*)d_in[5];
    const float* crop_w2       = (const float*)d_in[6];
    const float* crop_b2       = (const float*)d_in[7];
    const float* fuse_w        = (const float*)d_in[8];
    const float* fuse_b        = (const float*)d_in[9];
    const float* gate_w        = (const float*)d_in[10];
    const float* gate_b        = (const float*)d_in[11];
    float* out = (float*)d_out;

    char* ws = (char*)d_ws;
    size_t off = 0;
    auto alloc = [&](size_t bytes) -> void* {
        void* p = ws + off;
        off = (off + bytes + 255) & ~(size_t)255;
        return p;
    };
    int*            mode   = (int*)            alloc(16);
    int*            fpsidx = (int*)            alloc((size_t)B_SZ * MPT * 4);
    float4*         cp     = (float4*)         alloc((size_t)B_SZ * 15008 * 16);
    float*          xyzg   = (float*)          alloc((size_t)B_SZ * MPT * 3 * 4);
    float*          featg  = (float*)          alloc((size_t)B_SZ * CSEED * MPT * 4);
    float*          f1t    = (float*)          alloc((size_t)4 * B_SZ * MPT * 256 * 4);
    int*            selidx = (int*)            alloc((size_t)4 * B_SZ * MPT * 64 * 4);
    float*          selxyz = (float*)          alloc((size_t)4 * B_SZ * MPT * 64 * 3 * 4);
    unsigned short* w2bf   = (unsigned short*) alloc((size_t)4 * 512 * 256 * 2);
    float*          vpcat  = (float*)          alloc((size_t)B_SZ * 4 * 512 * MPT * 4);

    k_detect<<<1, 256, 0, stream>>>((const unsigned int*)mask_raw, mode);
    k_fps<<<B_SZ, FPS_T, 0, stream>>>(mask_raw, mode, seed_xyz, cp, fpsidx);
    k_gather<<<B_SZ * CSEED + B_SZ, 256, 0, stream>>>(seed_features, seed_xyz, fpsidx, featg, xyzg);
    k_w2bf<<<(4 * 512 * 256) / 256, 256, 0, stream>>>(crop_w2, w2bf);
    k_f1<<<128, 256, 0, stream>>>(featg, crop_w1, crop_b1, f1t);
    k_select<<<(B_SZ * MPT) / 4, 256, 0, stream>>>(xyzg, views_rot, selidx, selxyz);
    const int NS[4] = {16, 32, 32, 64};
    const int L2NS[4] = {4, 5, 5, 6};
    for (int s = 0; s < 4; ++s) {
        int jt = 64 >> L2NS[s];
        k_crop<<<B_SZ * (MPT / jt), 256, 0, stream>>>(s, NS[s], L2NS[s],
            f1t, crop_w1, w2bf, crop_b2, selidx, selxyz, vpcat);
    }
    k_out<<<128, 256, 0, stream>>>(vpcat, featg, fuse_w, fuse_b, gate_w, gate_b, out);
}

// Round 8
// 2152.651 us; speedup vs baseline: 1.9389x; 1.9389x over previous
//
#include <hip/hip_runtime.h>
#include <stdint.h>
#include <stddef.h>

#define B_SZ   2
#define N_PTS  15000
#define MPT    1024
#define CSEED  512
#define HMINF (-0.02f)
#define HMAXF (0.06f)

typedef __attribute__((ext_vector_type(8))) short bf16x8;
typedef __attribute__((ext_vector_type(4))) float f32x4;

__device__ inline unsigned short f2bf(float f) {
    unsigned u = __float_as_uint(f);
    unsigned r = (u + 0x7fffu + ((u >> 16) & 1u)) >> 16;   // RNE, finite inputs
    return (unsigned short)r;
}

// ---------------------------------------------------------------- mask dtype detect
__global__ void k_detect(const unsigned int* mraw, int* mode_out) {
    __shared__ int vi, vf;
    if (threadIdx.x == 0) { vi = 0; vf = 0; }
    __syncthreads();
    int li = 0, lf = 0;
    for (int i = threadIdx.x; i < (B_SZ * N_PTS) / 4; i += blockDim.x) {
        unsigned int u = mraw[i];
        if (u != 0u && u != 1u) li = 1;
        if (u != 0u && u != 0x3F800000u) lf = 1;
    }
    if (li) atomicOr(&vi, 1);
    if (lf) atomicOr(&vf, 1);
    __syncthreads();
    if (threadIdx.x == 0) *mode_out = (vi == 0) ? 0 : ((vf == 0) ? 1 : 2);
}

// ---------------------------------------------------------------- masked FPS v8
// 8-wave / 1-barrier loop (v6) + register-cached cell meta (v7): scan lane l
// of wave w owns cell w+8l — bbox/cmax/cidx/candidate all in registers, scan
// is pure VALU (no LDS -> no bank conflicts). pd in LDS (conflict-free
// lane-sequential), uniform while(ballot) cell processing, DPP argmax with
// tie fast-path, dpp8 lane-parallel cross-wave combine.
#define FPS_T     512
#define FPS_CAP   7936          // 124 cells x 64 pts; Mc>CAP -> exact fallback
#define NCELL_MAX 124

__device__ inline unsigned dpp_max_u32(unsigned v) {   // valid in lane 63
    unsigned t;
    t = (unsigned)__builtin_amdgcn_update_dpp(0, (int)v, 0x111, 0xf, 0xf, false); v = v > t ? v : t;
    t = (unsigned)__builtin_amdgcn_update_dpp(0, (int)v, 0x112, 0xf, 0xf, false); v = v > t ? v : t;
    t = (unsigned)__builtin_amdgcn_update_dpp(0, (int)v, 0x114, 0xf, 0xf, false); v = v > t ? v : t;
    t = (unsigned)__builtin_amdgcn_update_dpp(0, (int)v, 0x118, 0xf, 0xf, false); v = v > t ? v : t;
    t = (unsigned)__builtin_amdgcn_update_dpp(0, (int)v, 0x142, 0xf, 0xf, false); v = v > t ? v : t;
    t = (unsigned)__builtin_amdgcn_update_dpp(0, (int)v, 0x143, 0xf, 0xf, false); v = v > t ? v : t;
    return v;
}
__device__ inline int dpp_min_i32(int v) {             // valid in lane 63
    int t;
    t = __builtin_amdgcn_update_dpp(0x7fffffff, v, 0x111, 0xf, 0xf, false); v = v < t ? v : t;
    t = __builtin_amdgcn_update_dpp(0x7fffffff, v, 0x112, 0xf, 0xf, false); v = v < t ? v : t;
    t = __builtin_amdgcn_update_dpp(0x7fffffff, v, 0x114, 0xf, 0xf, false); v = v < t ? v : t;
    t = __builtin_amdgcn_update_dpp(0x7fffffff, v, 0x118, 0xf, 0xf, false); v = v < t ? v : t;
    t = __builtin_amdgcn_update_dpp(0x7fffffff, v, 0x142, 0xf, 0xf, false); v = v < t ? v : t;
    t = __builtin_amdgcn_update_dpp(0x7fffffff, v, 0x143, 0xf, 0xf, false); v = v < t ? v : t;
    return v;
}
__device__ inline unsigned dpp8_max_u32(unsigned v) {  // valid in lane 7
    unsigned t;
    t = (unsigned)__builtin_amdgcn_update_dpp(0, (int)v, 0x111, 0xf, 0xf, false); v = v > t ? v : t;
    t = (unsigned)__builtin_amdgcn_update_dpp(0, (int)v, 0x112, 0xf, 0xf, false); v = v > t ? v : t;
    t = (unsigned)__builtin_amdgcn_update_dpp(0, (int)v, 0x114, 0xf, 0xf, false); v = v > t ? v : t;
    return v;
}
__device__ inline int dpp8_min_i32(int v) {            // valid in lane 7
    int t;
    t = __builtin_amdgcn_update_dpp(0x7fffffff, v, 0x111, 0xf, 0xf, false); v = v < t ? v : t;
    t = __builtin_amdgcn_update_dpp(0x7fffffff, v, 0x112, 0xf, 0xf, false); v = v < t ? v : t;
    t = __builtin_amdgcn_update_dpp(0x7fffffff, v, 0x114, 0xf, 0xf, false); v = v < t ? v : t;
    return v;
}
__device__ inline float dpp_fmax64(float v) {          // valid in lane 63
    int t;
    t = __builtin_amdgcn_update_dpp((int)0xFF800000, __float_as_int(v), 0x111, 0xf, 0xf, false); v = fmaxf(v, __int_as_float(t));
    t = __builtin_amdgcn_update_dpp((int)0xFF800000, __float_as_int(v), 0x112, 0xf, 0xf, false); v = fmaxf(v, __int_as_float(t));
    t = __builtin_amdgcn_update_dpp((int)0xFF800000, __float_as_int(v), 0x114, 0xf, 0xf, false); v = fmaxf(v, __int_as_float(t));
    t = __builtin_amdgcn_update_dpp((int)0xFF800000, __float_as_int(v), 0x118, 0xf, 0xf, false); v = fmaxf(v, __int_as_float(t));
    t = __builtin_amdgcn_update_dpp((int)0xFF800000, __float_as_int(v), 0x142, 0xf, 0xf, false); v = fmaxf(v, __int_as_float(t));
    t = __builtin_amdgcn_update_dpp((int)0xFF800000, __float_as_int(v), 0x143, 0xf, 0xf, false); v = fmaxf(v, __int_as_float(t));
    return v;
}
__device__ inline float dpp_fmin64(float v) {          // valid in lane 63
    int t;
    t = __builtin_amdgcn_update_dpp(0x7F800000, __float_as_int(v), 0x111, 0xf, 0xf, false); v = fminf(v, __int_as_float(t));
    t = __builtin_amdgcn_update_dpp(0x7F800000, __float_as_int(v), 0x112, 0xf, 0xf, false); v = fminf(v, __int_as_float(t));
    t = __builtin_amdgcn_update_dpp(0x7F800000, __float_as_int(v), 0x114, 0xf, 0xf, false); v = fminf(v, __int_as_float(t));
    t = __builtin_amdgcn_update_dpp(0x7F800000, __float_as_int(v), 0x118, 0xf, 0xf, false); v = fminf(v, __int_as_float(t));
    t = __builtin_amdgcn_update_dpp(0x7F800000, __float_as_int(v), 0x142, 0xf, 0xf, false); v = fminf(v, __int_as_float(t));
    t = __builtin_amdgcn_update_dpp(0x7F800000, __float_as_int(v), 0x143, 0xf, 0xf, false); v = fminf(v, __int_as_float(t));
    return v;
}

__global__ __launch_bounds__(FPS_T, 1) void k_fps(
        const void* mask_raw, const int* mode_p, const float* seed_xyz,
        float4* cp, int* fps_idx)
{
    const int b    = blockIdx.x;
    const int tid  = threadIdx.x;
    const int wv   = tid >> 6;
    const int lane = tid & 63;
    const int mode = *mode_p;
    const int cpb  = b * 15008;

    __shared__ float4 ptsL[FPS_CAP];           // 126976 B (fallback: pd overlay)
    __shared__ float  s_pd[FPS_CAP];           // 31744 B (setup: s_cell overlay)
    __shared__ float  s_meta[NCELL_MAX * 6];   // bbox staging (one-time)
    __shared__ float4 s_pub4[2][8];
    __shared__ int    s_pubi[2][8];
    __shared__ int    s_wt[8];
    __shared__ int    s_total, s_start;
    __shared__ float  s_f[3];

    int* s_cell = (int*)s_pd;                  // 512 ints, setup-only overlay

    if (tid == 0) s_start = 0x7fffffff;
    s_cell[tid] = 0;
    __syncthreads();

    auto rd_mask = [&](int i) -> bool {
        if (mode == 0) return ((const int*)mask_raw)[b * N_PTS + i] != 0;
        if (mode == 1) return ((const unsigned int*)mask_raw)[b * N_PTS + i] != 0u;
        return ((const unsigned char*)mask_raw)[b * N_PTS + i] != 0;
    };
    auto cell_of = [&](float x, float y, float z) -> int {  // Morton 8x8x8
        int cx = (int)(x * 40.f); cx = cx < 0 ? 0 : (cx > 7 ? 7 : cx);
        int cy = (int)(y * 40.f); cy = cy < 0 ? 0 : (cy > 7 ? 7 : cy);
        int cz = (int)(z * 40.f); cz = cz < 0 ? 0 : (cz > 7 ? 7 : cz);
        int m = 0;
        #pragma unroll
        for (int q = 0; q < 3; ++q)
            m |= (((cx >> q) & 1) << (3*q+2)) | (((cy >> q) & 1) << (3*q+1)) | (((cz >> q) & 1) << (3*q));
        return m;
    };

    // pass 1: histogram + first masked index
    int myfirst = 0x7fffffff;
    for (int k = 0; k < 30; ++k) {
        int i = tid + k * FPS_T;
        if (i < N_PTS && rd_mask(i)) {
            if (i < myfirst) myfirst = i;
            float x = seed_xyz[(size_t)(b * N_PTS + i) * 3 + 0];
            float y = seed_xyz[(size_t)(b * N_PTS + i) * 3 + 1];
            float z = seed_xyz[(size_t)(b * N_PTS + i) * 3 + 2];
            atomicAdd(&s_cell[cell_of(x, y, z)], 1);
        }
    }
    if (myfirst != 0x7fffffff) atomicMin(&s_start, myfirst);
    __syncthreads();
    // parallel exclusive prefix over 512 grid cells
    {
        int v = s_cell[tid];
        int inc = v;
        #pragma unroll
        for (int d = 1; d < 64; d <<= 1) {
            int o = __shfl_up(inc, d, 64);
            if (lane >= d) inc += o;
        }
        if (lane == 63) s_wt[wv] = inc;
        __syncthreads();
        int off = 0;
        #pragma unroll
        for (int w = 0; w < 8; ++w) off += (w < wv) ? s_wt[w] : 0;
        s_cell[tid] = off + inc - v;
        if (tid == FPS_T - 1) s_total = off + inc;
    }
    __syncthreads();
    const int Mc = s_total;
    const int start = s_start;
    if (Mc == 0) {
        for (int m = tid; m < MPT; m += FPS_T) fps_idx[b * MPT + m] = 0;
        return;
    }

    // pass 2: scatter Morton-sorted into LDS (+ global mirror for fallback)
    for (int k = 0; k < 30; ++k) {
        int i = tid + k * FPS_T;
        if (i < N_PTS && rd_mask(i)) {
            float x = seed_xyz[(size_t)(b * N_PTS + i) * 3 + 0];
            float y = seed_xyz[(size_t)(b * N_PTS + i) * 3 + 1];
            float z = seed_xyz[(size_t)(b * N_PTS + i) * 3 + 2];
            int pos = atomicAdd(&s_cell[cell_of(x, y, z)], 1);
            float4 v4 = make_float4(x, y, z, __int_as_float(i));
            cp[cpb + pos] = v4;
            if (pos < FPS_CAP) ptsL[pos] = v4;
            if (i == start) { s_f[0] = x; s_f[1] = y; s_f[2] = z; }
        }
    }
    __threadfence_block();
    __syncthreads();

    if (Mc <= FPS_CAP) {
        // ================= main path: 8-wave, 1 barrier/iter =================
        const int ncell = (Mc + 63) >> 6;

        // one-time: per-cell bbox via wave DPP reduce -> s_meta
        for (int c = wv; c < ncell; c += 8) {
            bool val = (c * 64 + lane) < Mc;
            float4 v = ptsL[c * 64 + lane];
            float mnx = val ? v.x : 1e30f, mny = val ? v.y : 1e30f, mnz = val ? v.z : 1e30f;
            float mxx = val ? v.x : -1e30f, mxy = val ? v.y : -1e30f, mxz = val ? v.z : -1e30f;
            mnx = dpp_fmin64(mnx); mny = dpp_fmin64(mny); mnz = dpp_fmin64(mnz);
            mxx = dpp_fmax64(mxx); mxy = dpp_fmax64(mxy); mxz = dpp_fmax64(mxz);
            if (lane == 63) {
                s_meta[c*6+0] = mnx; s_meta[c*6+1] = mny; s_meta[c*6+2] = mnz;
                s_meta[c*6+3] = mxx; s_meta[c*6+4] = mxy; s_meta[c*6+5] = mxz;
            }
        }
        __syncthreads();
        for (int i = tid; i < (ncell << 6); i += FPS_T) s_pd[i] = 1e10f;

        // register-cached scan meta: lane l (<16) of wave w owns cell w+8l
        const int myc = wv + 8 * lane;
        const bool have = (lane < 16) && (myc < ncell);
        float Rnx=0.f,Rny=0.f,Rnz=0.f,Rxx=0.f,Rxy=0.f,Rxz=0.f;
        if (have) {
            Rnx = s_meta[myc*6+0]; Rny = s_meta[myc*6+1]; Rnz = s_meta[myc*6+2];
            Rxx = s_meta[myc*6+3]; Rxy = s_meta[myc*6+4]; Rxz = s_meta[myc*6+5];
        }
        float Rcm = have ? 1e10f : -1.f;       // cell max-pd (cached)
        int   Rci = 0x7fffffff;                // cell argmax idx (cached)
        float Rcx = 0.f, Rcy = 0.f, Rcz = 0.f; // cell candidate coords (cached)

        if (lane == 0) {                       // cell-less waves stay -1 forever
            s_pub4[0][wv] = make_float4(-1.f, 0.f, 0.f, 0.f);
            s_pub4[1][wv] = make_float4(-1.f, 0.f, 0.f, 0.f);
            s_pubi[0][wv] = 0x7fffffff;
            s_pubi[1][wv] = 0x7fffffff;
        }
        __syncthreads();

        float fx = s_f[0], fy = s_f[1], fz = s_f[2];
        int widx = start;
        int par = 0;

        #pragma unroll 1
        for (int m = 0; m < MPT; ++m) {
            if (tid == 0) fps_idx[b * MPT + m] = widx;

            // register-only skip scan (exact: skip only if no pd can change)
            float ex = fmaxf(fmaxf(Rnx - fx, fx - Rxx), 0.f);
            float ey = fmaxf(fmaxf(Rny - fy, fy - Rxy), 0.f);
            float ez = fmaxf(fmaxf(Rnz - fz, fz - Rxz), 0.f);
            float dmin2 = (ex*ex + ey*ey + ez*ez) * 0.99999f;
            bool active = have && (dmin2 < Rcm);
            unsigned long long rem = __ballot(active);

            #pragma unroll 1
            while (rem) {                      // wave-uniform over active cells
                int l0 = __ffsll(rem) - 1;
                rem &= rem - 1;
                int pb = ((wv + 8 * l0) << 6) + lane;
                bool vld = pb < Mc;
                float4 v = ptsL[pb];
                float pdv = s_pd[pb];
                float dx = __fsub_rn(v.x, fx);
                float dy = __fsub_rn(v.y, fy);
                float dz = __fsub_rn(v.z, fz);
                float d  = __fadd_rn(__fadd_rn(__fmul_rn(dx, dx), __fmul_rn(dy, dy)),
                                     __fmul_rn(dz, dz));
                float nd = fminf(pdv, d);
                if (vld) s_pd[pb] = nd;
                int ai = __float_as_int(v.w);
                unsigned vb = vld ? __float_as_uint(nd) : 0u;
                unsigned cmx = (unsigned)__builtin_amdgcn_readlane((int)dpp_max_u32(vb), 63);
                unsigned long long tb = __ballot(vld && vb == cmx);
                int wl;
                if (__popcll(tb) == 1) {
                    wl = __ffsll(tb) - 1;      // unique max: skip idx chain
                } else {
                    int ic = (vld && vb == cmx) ? ai : 0x7fffffff;
                    int cid = __builtin_amdgcn_readlane(dpp_min_i32(ic), 63);
                    wl = __ffsll(__ballot(vld && ai == cid)) - 1;
                }
                float ncm = __uint_as_float(cmx);
                int   nci = __builtin_amdgcn_readlane(ai, wl);
                float ncx = __int_as_float(__builtin_amdgcn_readlane(__float_as_int(v.x), wl));
                float ncy = __int_as_float(__builtin_amdgcn_readlane(__float_as_int(v.y), wl));
                float ncz = __int_as_float(__builtin_amdgcn_readlane(__float_as_int(v.z), wl));
                if (lane == l0) {              // owner scan lane updates cache
                    Rcm = ncm; Rci = nci; Rcx = ncx; Rcy = ncy; Rcz = ncz;
                }
            }

            // wave argmax over cached per-cell candidates (val desc, idx asc)
            unsigned v2 = (have && Rcm >= 0.f) ? __float_as_uint(Rcm) : 0u;
            unsigned wm = (unsigned)__builtin_amdgcn_readlane((int)dpp_max_u32(v2), 63);
            unsigned long long t2 = __ballot(have && v2 == wm);
            if (t2) {
                int wl2, gi;
                if (__popcll(t2) == 1) {
                    wl2 = __ffsll(t2) - 1;
                    gi = __builtin_amdgcn_readlane(Rci, wl2);
                } else {
                    int ic2 = (have && v2 == wm) ? Rci : 0x7fffffff;
                    gi = __builtin_amdgcn_readlane(dpp_min_i32(ic2), 63);
                    wl2 = __ffsll(__ballot(have && v2 == wm && Rci == gi)) - 1;
                }
                if (lane == wl2) {             // winner scan lane publishes
                    s_pub4[par][wv] = make_float4(__uint_as_float(wm), Rcx, Rcy, Rcz);
                    s_pubi[par][wv] = gi;
                }
            }
            __syncthreads();
            // lane-parallel global combine over 8 wave slots
            {
                float4 p4 = s_pub4[par][lane & 7];
                int    pi = s_pubi[par][lane & 7];
                unsigned vb2 = (lane < 8 && p4.x >= 0.f) ? __float_as_uint(p4.x) : 0u;
                int pid2 = (lane < 8) ? pi : 0x7fffffff;
                unsigned gmax = (unsigned)__builtin_amdgcn_readlane((int)dpp8_max_u32(vb2), 7);
                int ic3 = (vb2 == gmax && lane < 8) ? pid2 : 0x7fffffff;
                int gidx = __builtin_amdgcn_readlane(dpp8_min_i32(ic3), 7);
                unsigned long long gm = __ballot(lane < 8 && vb2 == gmax && pid2 == gidx);
                int wl3 = __ffsll(gm) - 1;
                fx = __int_as_float(__builtin_amdgcn_readlane(__float_as_int(p4.y), wl3));
                fy = __int_as_float(__builtin_amdgcn_readlane(__float_as_int(p4.z), wl3));
                fz = __int_as_float(__builtin_amdgcn_readlane(__float_as_int(p4.w), wl3));
                widx = gidx;
            }
            par ^= 1;
        }
    } else {
        // ============ fallback (Mc > 7936): L2 coords, LDS pd ============
        const int L = (Mc + FPS_T - 1) / FPS_T;
        float* pdL = (float*)ptsL;             // Mc <= 15000 -> 60 KB
        for (int c = tid; c < Mc; c += FPS_T) pdL[c] = 1e10f;
        if (lane == 0) {
            s_pub4[0][wv] = make_float4(-1.f, 0.f, 0.f, 0.f);
            s_pub4[1][wv] = make_float4(-1.f, 0.f, 0.f, 0.f);
            s_pubi[0][wv] = 0x7fffffff;
            s_pubi[1][wv] = 0x7fffffff;
        }
        __syncthreads();
        float fx = s_f[0], fy = s_f[1], fz = s_f[2];
        int widx = start;
        int par = 0;
        for (int m = 0; m < MPT; ++m) {
            if (tid == 0) fps_idx[b * MPT + m] = widx;
            float nv = -1.f; int ni = 0x7fffffff;
            float nx = 0.f, ny = 0.f, nz = 0.f;
            for (int k = 0; k < L; ++k) {
                int c = tid * L + k;
                if (c < Mc) {
                    float4 v = cp[cpb + c];
                    float dx = __fsub_rn(v.x, fx);
                    float dy = __fsub_rn(v.y, fy);
                    float dz = __fsub_rn(v.z, fz);
                    float d  = __fadd_rn(__fadd_rn(__fmul_rn(dx, dx), __fmul_rn(dy, dy)),
                                         __fmul_rn(dz, dz));
                    float nd = fminf(pdL[c], d);
                    pdL[c] = nd;
                    int oi = __float_as_int(v.w);
                    bool bt = (nd > nv) || (nd == nv && oi < ni);
                    nv = bt ? nd : nv; ni = bt ? oi : ni;
                    nx = bt ? v.x : nx; ny = bt ? v.y : ny; nz = bt ? v.z : nz;
                }
            }
            unsigned vb = (nv >= 0.f) ? __float_as_uint(nv) : 0u;
            unsigned wmax = (unsigned)__builtin_amdgcn_readlane((int)dpp_max_u32(vb), 63);
            int icand = (vb == wmax) ? ni : 0x7fffffff;
            int wmin = __builtin_amdgcn_readlane(dpp_min_i32(icand), 63);
            if ((vb == wmax) && (ni == wmin) && vb != 0u) {
                s_pub4[par][wv] = make_float4(nv, nx, ny, nz);
                s_pubi[par][wv] = ni;
            }
            __syncthreads();
            {
                float bvv = -2.f; int bii = 0x7fffffff;
                float nfx = 0.f, nfy = 0.f, nfz = 0.f;
                #pragma unroll
                for (int w = 0; w < 8; ++w) {
                    float4 c4 = s_pub4[par][w];
                    int ci2 = s_pubi[par][w];
                    bool bt = (c4.x > bvv) || (c4.x == bvv && ci2 < bii);
                    bvv = bt ? c4.x : bvv; bii = bt ? ci2 : bii;
                    nfx = bt ? c4.y : nfx; nfy = bt ? c4.z : nfy; nfz = bt ? c4.w : nfz;
                }
                fx = nfx; fy = nfy; fz = nfz; widx = bii;
            }
            par ^= 1;
        }
    }
}

// ---------------------------------------------------------------- gathers
__global__ void k_gather(const float* seed_features, const float* seed_xyz,
                         const int* fps_idx, float* feat_g, float* xyz_g)
{
    int e = blockIdx.x;
    if (e < B_SZ * CSEED) {
        int b = e >> 9, c = e & (CSEED - 1);
        const float* src = seed_features + (size_t)(b * CSEED + c) * N_PTS;
        float* dst = feat_g + (size_t)(b * CSEED + c) * MPT;
        const int* idx = fps_idx + b * MPT;
        for (int m = threadIdx.x; m < MPT; m += blockDim.x) dst[m] = src[idx[m]];
    } else {
        int b = e - B_SZ * CSEED;
        const int* idx = fps_idx + b * MPT;
        for (int m = threadIdx.x; m < MPT; m += blockDim.x) {
            int p = idx[m];
            xyz_g[(size_t)(b * MPT + m) * 3 + 0] = seed_xyz[(size_t)(b * N_PTS + p) * 3 + 0];
            xyz_g[(size_t)(b * MPT + m) * 3 + 1] = seed_xyz[(size_t)(b * N_PTS + p) * 3 + 1];
            xyz_g[(size_t)(b * MPT + m) * 3 + 2] = seed_xyz[(size_t)(b * N_PTS + p) * 3 + 2];
        }
    }
}

// ---------------------------------------------------------------- W2 -> bf16 (same layout)
__global__ void k_w2bf(const float* crop_w2, unsigned short* w2bf) {
    int i = blockIdx.x * blockDim.x + threadIdx.x;
    if (i < 4 * 512 * 256) w2bf[i] = f2bf(crop_w2[i]);
}

// ---------------------------------------------------------------- F1T = feat_g^T * W1f^T + b1
__global__ __launch_bounds__(256) void k_f1(const float* feat_g, const float* crop_w1,
                                            const float* crop_b1, float* f1t)
{
    const int blk = blockIdx.x;
    const int pt = blk & 15;
    const int b  = (blk >> 4) & 1;
    const int s  = blk >> 5;
    const int p0 = pt * 64;
    __shared__ float A[16][64];
    __shared__ float Bm[16][256];
    const int tid = threadIdx.x;
    const int pg = tid & 15, og = tid >> 4;
    float acc[4][16];
    #pragma unroll
    for (int i = 0; i < 4; ++i)
        #pragma unroll
        for (int j = 0; j < 16; ++j) acc[i][j] = 0.f;

    for (int kc = 0; kc < CSEED; kc += 16) {
        __syncthreads();
        {
            int r = tid >> 4, pp = (tid & 15) * 4;
            *(float4*)&A[r][pp] =
                *(const float4*)&feat_g[(size_t)(b * CSEED + kc + r) * MPT + p0 + pp];
            #pragma unroll
            for (int r2 = 0; r2 < 16; ++r2)
                Bm[r2][tid] = crop_w1[(size_t)(s * 256 + tid) * 515 + 3 + kc + r2];
        }
        __syncthreads();
        #pragma unroll
        for (int r = 0; r < 16; ++r) {
            float4 a4 = *(const float4*)&A[r][pg * 4];
            float av[4] = {a4.x, a4.y, a4.z, a4.w};
            float bv[16];
            #pragma unroll
            for (int q = 0; q < 4; ++q) {
                float4 b4 = *(const float4*)&Bm[r][og * 16 + q * 4];
                bv[q*4+0] = b4.x; bv[q*4+1] = b4.y; bv[q*4+2] = b4.z; bv[q*4+3] = b4.w;
            }
            #pragma unroll
            for (int i = 0; i < 4; ++i)
                #pragma unroll
                for (int j = 0; j < 16; ++j)
                    acc[i][j] += av[i] * bv[j];
        }
    }
    #pragma unroll
    for (int i = 0; i < 4; ++i) {
        size_t row = (size_t)((s * B_SZ + b) * MPT + p0 + pg * 4 + i) * 256;
        #pragma unroll
        for (int q = 0; q < 4; ++q) {
            float4 o4;
            o4.x = acc[i][q*4+0] + crop_b1[s*256 + og*16 + q*4+0];
            o4.y = acc[i][q*4+1] + crop_b1[s*256 + og*16 + q*4+1];
            o4.z = acc[i][q*4+2] + crop_b1[s*256 + og*16 + q*4+2];
            o4.w = acc[i][q*4+3] + crop_b1[s*256 + og*16 + q*4+3];
            *(float4*)&f1t[row + og * 16 + q * 4] = o4;
        }
    }
}

// ---------------------------------------------------------------- local coords + neighbor select
__global__ __launch_bounds__(256) void k_select(const float* xyz_g, const float* views_rot,
                                                int* sel_idx, float* sel_xyz)
{
    const int wv = threadIdx.x >> 6;
    const int lane = threadIdx.x & 63;
    const int gj = blockIdx.x * 4 + wv;
    const int b = gj >> 10, j = gj & (MPT - 1);

    const float cx = xyz_g[(size_t)(b * MPT + j) * 3 + 0];
    const float cy = xyz_g[(size_t)(b * MPT + j) * 3 + 1];
    const float cz = xyz_g[(size_t)(b * MPT + j) * 3 + 2];
    const float* R = views_rot + (size_t)(b * MPT + j) * 9;
    const float r00 = R[0], r01 = R[1], r02 = R[2];
    const float r10 = R[3], r11 = R[4], r12 = R[5];
    const float r20 = R[6], r21 = R[7], r22 = R[8];

    const float R2C[4] = { (float)(0.025 * 0.025), (float)(0.0375 * 0.0375),
                           (float)(0.05 * 0.05),   (float)(0.075 * 0.075) };
    const int NSs[4] = {16, 32, 32, 64};

    __shared__ float s_zloc[4][3];
    __shared__ int   s_padk[4][4];
    __shared__ float s_padx[4][4][3];

    int cnt[4] = {0, 0, 0, 0};

    for (int ch = 0; ch < 16; ++ch) {
        int k = ch * 64 + lane;
        float x = xyz_g[(size_t)(b * MPT + k) * 3 + 0];
        float y = xyz_g[(size_t)(b * MPT + k) * 3 + 1];
        float z = xyz_g[(size_t)(b * MPT + k) * 3 + 2];
        float rx = __fsub_rn(x, cx), ry = __fsub_rn(y, cy), rz = __fsub_rn(z, cz);
        float l0 = __fadd_rn(__fadd_rn(__fmul_rn(rx, r00), __fmul_rn(ry, r10)), __fmul_rn(rz, r20));
        float l1 = __fadd_rn(__fadd_rn(__fmul_rn(rx, r01), __fmul_rn(ry, r11)), __fmul_rn(rz, r21));
        float l2 = __fadd_rn(__fadd_rn(__fmul_rn(rx, r02), __fmul_rn(ry, r12)), __fmul_rn(rz, r22));
        float r2 = __fadd_rn(__fmul_rn(l1, l1), __fmul_rn(l2, l2));
        bool inh = (l0 >= HMINF) && (l0 <= HMAXF);
        if (ch == 0 && lane == 0) { s_zloc[wv][0] = l0; s_zloc[wv][1] = l1; s_zloc[wv][2] = l2; }
        #pragma unroll
        for (int sc = 0; sc < 4; ++sc) {
            bool v = inh && (r2 < R2C[sc]);
            unsigned long long bal = __ballot(v);
            int pre = __popcll(bal & ((1ull << lane) - 1ull));
            int p = cnt[sc] + pre;
            if (v && p < NSs[sc]) {
                size_t sb = ((size_t)(sc * B_SZ + b) * MPT + j) * 64 + p;
                sel_idx[sb] = k;
                sel_xyz[sb * 3 + 0] = l0;
                sel_xyz[sb * 3 + 1] = l1;
                sel_xyz[sb * 3 + 2] = l2;
                if (p == 0) {
                    s_padk[wv][sc] = k;
                    s_padx[wv][sc][0] = l0; s_padx[wv][sc][1] = l1; s_padx[wv][sc][2] = l2;
                }
            }
            cnt[sc] += __popcll(bal);
        }
    }
    __syncthreads();
    #pragma unroll
    for (int sc = 0; sc < 4; ++sc) {
        int cs = cnt[sc];
        int pk; float a0, a1, a2;
        if (cs > 0) { pk = s_padk[wv][sc]; a0 = s_padx[wv][sc][0]; a1 = s_padx[wv][sc][1]; a2 = s_padx[wv][sc][2]; }
        else        { pk = 0; a0 = s_zloc[wv][0]; a1 = s_zloc[wv][1]; a2 = s_zloc[wv][2]; }
        for (int n = cs + lane; n < NSs[sc]; n += 64) {
            size_t sb = ((size_t)(sc * B_SZ + b) * MPT + j) * 64 + n;
            sel_idx[sb] = pk;
            sel_xyz[sb * 3 + 0] = a0; sel_xyz[sb * 3 + 1] = a1; sel_xyz[sb * 3 + 2] = a2;
        }
    }
}

// ---------------------------------------------------------------- crop MLP via bf16 MFMA
__global__ __launch_bounds__(256) void k_crop(
        const int s, const int ns, const int log2ns,
        const float* f1t, const float* crop_w1, const unsigned short* w2bf,
        const float* crop_b2, const int* sel_idx, const float* sel_xyz, float* vp_cat)
{
    const int tid = threadIdx.x;
    const int jt = 64 >> log2ns;
    const int nj = MPT / jt;
    const int b = blockIdx.x / nj;
    const int jbase = (blockIdx.x % nj) * jt;

    __shared__ unsigned short h1T[64 * 264];   // [col][c] bf16, stride 264
    __shared__ float w1xa[3 * 256];
    __shared__ float pooled[512 * 4];          // [o][wave]

    for (int i = tid; i < 768; i += 256) {
        int a = i >> 8, o = i & 255;
        w1xa[i] = crop_w1[(size_t)(s * 256 + o) * 515 + a];
    }
    __syncthreads();

    // phase 1: h1 = relu(f1row + W1x*xyz) -> bf16 -> h1T
    {
        const int col = tid & 63;
        const int cq = tid >> 6;
        const int jl = col >> log2ns;
        const int nn = col & (ns - 1);
        const size_t sb = ((size_t)(s * B_SZ + b) * MPT + jbase + jl) * 64 + nn;
        const int p = sel_idx[sb];
        const float gx = sel_xyz[sb * 3 + 0];
        const float gy = sel_xyz[sb * 3 + 1];
        const float gz = sel_xyz[sb * 3 + 2];
        const float* f1row = f1t + (size_t)((s * B_SZ + b) * MPT + p) * 256;
        #pragma unroll
        for (int c4 = 0; c4 < 16; ++c4) {
            int c0 = cq * 64 + c4 * 4;
            float4 fv = *(const float4*)&f1row[c0];
            float v0 = fmaxf(fv.x + w1xa[c0+0]*gx + w1xa[256+c0+0]*gy + w1xa[512+c0+0]*gz, 0.f);
            float v1 = fmaxf(fv.y + w1xa[c0+1]*gx + w1xa[256+c0+1]*gy + w1xa[512+c0+1]*gz, 0.f);
            float v2 = fmaxf(fv.z + w1xa[c0+2]*gx + w1xa[256+c0+2]*gy + w1xa[512+c0+2]*gz, 0.f);
            float v3 = fmaxf(fv.w + w1xa[c0+3]*gx + w1xa[256+c0+3]*gy + w1xa[512+c0+3]*gz, 0.f);
            unsigned lo = (unsigned)f2bf(v0) | ((unsigned)f2bf(v1) << 16);
            unsigned hi = (unsigned)f2bf(v2) | ((unsigned)f2bf(v3) << 16);
            *(uint2*)&h1T[col * 264 + c0] = make_uint2(lo, hi);
        }
    }
    __syncthreads();

    // phase 2: per-wave MFMA over 32 o-tiles
    {
        const int wv = tid >> 6;
        const int lane = tid & 63;
        const int lm = lane & 15, lq = lane >> 4;

        bf16x8 afr[8];                         // h1 A-frags: loaded once
        #pragma unroll
        for (int kk = 0; kk < 8; ++kk)
            afr[kk] = *(const bf16x8*)&h1T[(wv * 16 + lm) * 264 + kk * 32 + lq * 8];

        const unsigned short* wbase = w2bf + (size_t)s * 512 * 256;
        auto ldb = [&](int ot, int kk) -> bf16x8 {
            return *(const bf16x8*)&wbase[(size_t)(ot * 16 + lm) * 256 + kk * 32 + lq * 8];
        };

        bf16x8 bbA[8], bbB[8];
        #pragma unroll
        for (int kk = 0; kk < 8; ++kk) bbA[kk] = ldb(0, kk);

        #pragma unroll 1
        for (int op = 0; op < 16; ++op) {
            const int ot0 = op * 2, ot1 = op * 2 + 1;
            #pragma unroll
            for (int kk = 0; kk < 8; ++kk) bbB[kk] = ldb(ot1, kk);
            {
                f32x4 acc = {0.f, 0.f, 0.f, 0.f};
                #pragma unroll
                for (int kk = 0; kk < 8; ++kk)
                    acc = __builtin_amdgcn_mfma_f32_16x16x32_bf16(afr[kk], bbA[kk], acc, 0, 0, 0);
                float mx = fmaxf(fmaxf(acc[0], acc[1]), fmaxf(acc[2], acc[3]));
                mx = fmaxf(mx, __shfl_xor(mx, 16, 64));
                mx = fmaxf(mx, __shfl_xor(mx, 32, 64));
                if (lane < 16) pooled[(ot0 * 16 + lane) * 4 + wv] = mx;
            }
            if (op < 15) {
                #pragma unroll
                for (int kk = 0; kk < 8; ++kk) bbA[kk] = ldb(ot1 + 1, kk);
            }
            {
                f32x4 acc = {0.f, 0.f, 0.f, 0.f};
                #pragma unroll
                for (int kk = 0; kk < 8; ++kk)
                    acc = __builtin_amdgcn_mfma_f32_16x16x32_bf16(afr[kk], bbB[kk], acc, 0, 0, 0);
                float mx = fmaxf(fmaxf(acc[0], acc[1]), fmaxf(acc[2], acc[3]));
                mx = fmaxf(mx, __shfl_xor(mx, 16, 64));
                mx = fmaxf(mx, __shfl_xor(mx, 32, 64));
                if (lane < 16) pooled[(ot1 * 16 + lane) * 4 + wv] = mx;
            }
        }
    }
    __syncthreads();

    // epilogue: combine wave partials per center, +b2, relu, store
    const int g = ns >> 4;                     // wave-slots per center: 1,2,4
    for (int t = tid; t < 512 * jt; t += 256) {
        int o = t & 511, j2 = t >> 9;
        float v = pooled[o * 4 + j2 * g];
        for (int q = 1; q < g; ++q) v = fmaxf(v, pooled[o * 4 + j2 * g + q]);
        v = fmaxf(v + crop_b2[s * 512 + o], 0.f);
        vp_cat[((size_t)(b * 4 + s) * 512 + o) * MPT + jbase + j2] = v;
    }
}

// ---------------------------------------------------------------- fuse + gate + output
__global__ __launch_bounds__(256) void k_out(
        const float* vp_cat, const float* feat_g,
        const float* fuse_w, const float* fuse_b,
        const float* gate_w, const float* gate_b, float* out)
{
    const int blk = blockIdx.x;
    const int mt = blk & 15, ot = (blk >> 4) & 3, b = blk >> 6;
    const int o0b = ot * 128, m0b = mt * 64;
    __shared__ float A[16 * 128];
    __shared__ float Bm[16 * 64];
    const int tid = threadIdx.x;
    const int og = tid >> 4, mg = tid & 15;
    float acc1[8][4], acc2[8][4];
    #pragma unroll
    for (int i = 0; i < 8; ++i)
        #pragma unroll
        for (int jq = 0; jq < 4; ++jq) { acc1[i][jq] = 0.f; acc2[i][jq] = 0.f; }

    for (int kc = 0; kc < 2048; kc += 16) {
        __syncthreads();
        {
            int oo = tid >> 1, r0 = (tid & 1) * 8;
            const float* srow = fuse_w + (size_t)(o0b + oo) * 2048 + kc + r0;
            float4 u0 = *(const float4*)srow;
            float4 u1 = *(const float4*)(srow + 4);
            A[(r0 + 0) * 128 + oo] = u0.x; A[(r0 + 1) * 128 + oo] = u0.y;
            A[(r0 + 2) * 128 + oo] = u0.z; A[(r0 + 3) * 128 + oo] = u0.w;
            A[(r0 + 4) * 128 + oo] = u1.x; A[(r0 + 5) * 128 + oo] = u1.y;
            A[(r0 + 6) * 128 + oo] = u1.z; A[(r0 + 7) * 128 + oo] = u1.w;
            int r = tid >> 4, mm = (tid & 15) * 4;
            *(float4*)&Bm[r * 64 + mm] =
                *(const float4*)&vp_cat[((size_t)b * 2048 + kc + r) * MPT + m0b + mm];
        }
        __syncthreads();
        #pragma unroll
        for (int r = 0; r < 16; ++r) {
            float4 a0 = *(const float4*)&A[r * 128 + og * 8];
            float4 a1 = *(const float4*)&A[r * 128 + og * 8 + 4];
            float4 bb = *(const float4*)&Bm[r * 64 + mg * 4];
            float av[8] = {a0.x,a0.y,a0.z,a0.w, a1.x,a1.y,a1.z,a1.w};
            float bv[4] = {bb.x, bb.y, bb.z, bb.w};
            #pragma unroll
            for (int oi = 0; oi < 8; ++oi)
                #pragma unroll
                for (int mi = 0; mi < 4; ++mi)
                    acc1[oi][mi] += av[oi] * bv[mi];
        }
    }
    for (int kc = 0; kc < 512; kc += 16) {
        __syncthreads();
        {
            int oo = tid >> 1, r0 = (tid & 1) * 8;
            const float* srow = gate_w + (size_t)(o0b + oo) * 512 + kc + r0;
            float4 u0 = *(const float4*)srow;
            float4 u1 = *(const float4*)(srow + 4);
            A[(r0 + 0) * 128 + oo] = u0.x; A[(r0 + 1) * 128 + oo] = u0.y;
            A[(r0 + 2) * 128 + oo] = u0.z; A[(r0 + 3) * 128 + oo] = u0.w;
            A[(r0 + 4) * 128 + oo] = u1.x; A[(r0 + 5) * 128 + oo] = u1.y;
            A[(r0 + 6) * 128 + oo] = u1.z; A[(r0 + 7) * 128 + oo] = u1.w;
            int r = tid >> 4, mm = (tid & 15) * 4;
            *(float4*)&Bm[r * 64 + mm] =
                *(const float4*)&feat_g[((size_t)b * CSEED + kc + r) * MPT + m0b + mm];
        }
        __syncthreads();
        #pragma unroll
        for (int r = 0; r < 16; ++r) {
            float4 a0 = *(const float4*)&A[r * 128 + og * 8];
            float4 a1 = *(const float4*)&A[r * 128 + og * 8 + 4];
            float4 bb = *(const float4*)&Bm[r * 64 + mg * 4];
            float av[8] = {a0.x,a0.y,a0.z,a0.w, a1.x,a1.y,a1.z,a1.w};
            float bv[4] = {bb.x, bb.y, bb.z, bb.w};
            #pragma unroll
            for (int oi = 0; oi < 8; ++oi)
                #pragma unroll
                for (int mi = 0; mi < 4; ++mi)
                    acc2[oi][mi] += av[oi] * bv[mi];
        }
    }
    #pragma unroll
    for (int oi = 0; oi < 8; ++oi) {
        int o = o0b + og * 8 + oi;
        float fb = fuse_b[o], gb = gate_b[o];
        #pragma unroll
        for (int mi = 0; mi < 4; ++mi) {
            int m = m0b + mg * 4 + mi;
            float f = acc1[oi][mi] + fb;
            float gl = acc2[oi][mi] + gb;
            float gt = 1.f / (1.f + __expf(-gl));
            float fg = feat_g[((size_t)b * CSEED + o) * MPT + m];
            out[((size_t)b * CSEED + o) * MPT + m] = f + gt * fg;
        }
    }
}

// ---------------------------------------------------------------- launcher
extern "C" void kernel_launch(void* const* d_in, const int* in_sizes, int n_in,
                              void* d_out, int out_size, void* d_ws, size_t ws_size,
                              hipStream_t stream) {
    const float* seed_xyz      = (const float*)d_in[0];
    const float* seed_features = (const float*)d_in[1];
    const void*  mask_raw      = d_in[2];
    const float* views_rot     = (const float*)d_in[3];
    const float* crop_w1       = (const float*)d_in[4];
    const float* crop_b1       = (const float*)d_in[5];
    const float* crop_w2       = (const float*)d_in[6];
    const float* crop_b2       = (const float*)d_in[7];
    const float* fuse_w        = (const float*)d_in[8];
    const float* fuse_b        = (const float*)d_in[9];
    const float* gate_w        = (const float*)d_in[10];
    const float* gate_b        = (const float*)d_in[11];
    float* out = (float*)d_out;

    char* ws = (char*)d_ws;
    size_t off = 0;
    auto alloc = [&](size_t bytes) -> void* {
        void* p = ws + off;
        off = (off + bytes + 255) & ~(size_t)255;
        return p;
    };
    int*            mode   = (int*)            alloc(16);
    int*            fpsidx = (int*)            alloc((size_t)B_SZ * MPT * 4);
    float4*         cp     = (float4*)         alloc((size_t)B_SZ * 15008 * 16);
    float*          xyzg   = (float*)          alloc((size_t)B_SZ * MPT * 3 * 4);
    float*          featg  = (float*)          alloc((size_t)B_SZ * CSEED * MPT * 4);
    float*          f1t    = (float*)          alloc((size_t)4 * B_SZ * MPT * 256 * 4);
    int*            selidx = (int*)            alloc((size_t)4 * B_SZ * MPT * 64 * 4);
    float*          selxyz = (float*)          alloc((size_t)4 * B_SZ * MPT * 64 * 3 * 4);
    unsigned short* w2bf   = (unsigned short*) alloc((size_t)4 * 512 * 256 * 2);
    float*          vpcat  = (float*)          alloc((size_t)B_SZ * 4 * 512 * MPT * 4);

    k_detect<<<1, 256, 0, stream>>>((const unsigned int*)mask_raw, mode);
    k_fps<<<B_SZ, FPS_T, 0, stream>>>(mask_raw, mode, seed_xyz, cp, fpsidx);
    k_gather<<<B_SZ * CSEED + B_SZ, 256, 0, stream>>>(seed_features, seed_xyz, fpsidx, featg, xyzg);
    k_w2bf<<<(4 * 512 * 256) / 256, 256, 0, stream>>>(crop_w2, w2bf);
    k_f1<<<128, 256, 0, stream>>>(featg, crop_w1, crop_b1, f1t);
    k_select<<<(B_SZ * MPT) / 4, 256, 0, stream>>>(xyzg, views_rot, selidx, selxyz);
    const int NS[4] = {16, 32, 32, 64};
    const int L2NS[4] = {4, 5, 5, 6};
    for (int s = 0; s < 4; ++s) {
        int jt = 64 >> L2NS[s];
        k_crop<<<B_SZ * (MPT / jt), 256, 0, stream>>>(s, NS[s], L2NS[s],
            f1t, crop_w1, w2bf, crop_b2, selidx, selxyz, vpcat);
    }
    k_out<<<128, 256, 0, stream>>>(vpcat, featg, fuse_w, fuse_b, gate_w, gate_b, out);
}